// Round 5
// baseline (1953.685 us; speedup 1.0000x reference)
//
#include <hip/hip_runtime.h>
#include <math.h>

// Problem constants (shapes fixed by setup_inputs)
#define NV 4
#define NREC 240
#define TT 32
#define EDIM 300
#define HID 256
#define G4 1024
#define OC 32
#define NCLS 20
#define IMGF 6272     // OC*14*14
#define FEATD 6784
#define NROW 7680
#define IMG_PIX 50176

typedef __attribute__((ext_vector_type(8))) short short8;
typedef __attribute__((ext_vector_type(16))) float floatx16;
typedef __attribute__((ext_vector_type(2))) _Float16 h2;
typedef unsigned short u16;

__device__ inline u16 f2bf(float x) {
    unsigned int u = __float_as_uint(x);
    unsigned int r = u + 0x7FFFu + ((u >> 16) & 1u);
    return (u16)(r >> 16);
}

// ---------------- fused prep: conv weights (pre-rotated by 1 q-slot), Whh fp16,
// Wih bf16 (both layers). grid = 4096 x 256 = 2^20 threads.
__global__ void prep_all_kernel(const float* __restrict__ cw,
                                const float* __restrict__ w0, const float* __restrict__ w1,
                                const float* __restrict__ wih0, const float* __restrict__ wih1,
                                u16* __restrict__ wprep, _Float16* __restrict__ whhH,
                                u16* __restrict__ wihb0, u16* __restrict__ wihb1) {
    int idx = blockIdx.x * 256 + threadIdx.x;   // < 2^20
    // ---- whhH[l][d][k2][hu][g][p] fp16 (1,048,576 elems) ----
    {
        int p  = idx & 1;
        int g  = (idx >> 1) & 3;
        int hu = (idx >> 3) & 255;
        int k2 = (idx >> 11) & 127;
        int d  = (idx >> 18) & 1;
        int l  = (idx >> 19) & 1;
        const float* W = l ? w1 : w0;
        whhH[idx] = (_Float16)W[((size_t)d * G4 + g * 256 + hu) * 256 + k2 * 2 + p];
    }
    // ---- wihb1: [2][1024][512] bf16, K==Kp==512 (1,048,576 elems) ----
    wihb1[idx] = f2bf(wih1[idx]);
    // ---- wihb0: [2][1024][320] bf16, K=300 padded (655,360 elems) ----
    if (idx < 2 * 1024 * 320) {
        int k = idx % 320;
        int j = idx / 320;
        wihb0[idx] = (k < 300) ? f2bf(wih0[(size_t)j * 300 + k]) : (u16)0;
    }
    // ---- wprep[r][oc][qd] bf16, PRE-ROTATED: slot qd holds weight(kh=(qd+1)&7) ----
    if (idx < 64 * 32 * 8) {
        int qd = idx & 7;
        int oc = (idx >> 3) & 31;
        int r  = idx >> 8;
        int kh = (qd + 1) & 7;
        float v = 0.f;
        if (r < 63 && kh < 7) {
            int pl = r / 7, kw = r % 7;
            int c = pl / 3, kd = pl % 3;
            v = cw[(size_t)oc * 441 + c * 147 + kd * 49 + kh * 7 + kw];
        }
        wprep[idx] = f2bf(v);
    }
}

// ---------------- conv3d + 8x8 spatial maxpool, rolling-window implicit MFMA GEMM
// B fragments hoisted to registers; per-y rotation = static even word-rename.
#define REG_PITCH 1840
#define PLANE_PITCH 3680
#define CONV_LDS_TOTAL 33120     // input staging only (9 planes)

template<int E>
__device__ __attribute__((always_inline))
static void conv_y_body(int y, unsigned char* lds, const float* __restrict__ img,
                        const short8* Bc, const float* __restrict__ cb,
                        float* __restrict__ spool, float* pmax,
                        int vf, int f, int u, int rowsel, int xe, int half, int m, int wv)
{
    if ((y & 7) == 0) {
#pragma unroll
        for (int rc = 0; rc < 4; ++rc) pmax[rc] = -3.0e38f;
    }
    // ---- prefetch next 2 image rows (z = 2y+4, 2y+5) into registers ----
    int zz = 2 * y + 4 + rowsel;
    int zc = zz > 223 ? 223 : zz;
    bool zok = zz <= 223;
    int col = 2 * u - 4;
    int colc = col < 0 ? 0 : (col > 222 ? 222 : col);
    bool uok = (u >= 2 && u <= 113);
    float2 pf[9];
#pragma unroll
    for (int p = 0; p < 9; ++p) {
        int c = p / 3, kd = p - c * 3;
        int zp = vf + kd - 1;
        int zpc = zp < 0 ? 0 : (zp > 255 ? 255 : zp);   // clamp: address always in-bounds
        pf[p] = *(const float2*)(img + ((size_t)zpc * 3 + c) * IMG_PIX
                                 + (size_t)zc * 224 + colc);
    }
    // ---- MFMA pass: A from LDS, B from registers with static rotation E ----
    floatx16 acc = {0,0,0,0,0,0,0,0,0,0,0,0,0,0,0,0};
#pragma unroll
    for (int kk = 0; kk < 32; ++kk) {
        int r = kk * 2 + half;
        int pl = r / 7;
        int kw = r - pl * 7;
        bool pad = (pl > 8);
        if (pad) { pl = 8; kw = 6; }     // r=63: A addr clamped, B already all-zero
        int reg = (kw + 1) & 1;
        int hw  = (kw + 1) >> 1;
        short8 af = *(const short8*)(lds + pl * PLANE_PITCH + reg * REG_PITCH + (xe + hw) * 16);
        short8 b = Bc[kk];
        short8 bfr = __builtin_shufflevector(b, b,
            (0+E)&7, (1+E)&7, (2+E)&7, (3+E)&7, (4+E)&7, (5+E)&7, (6+E)&7, (7+E)&7);
        acc = __builtin_amdgcn_mfma_f32_32x32x16_bf16(af, bfr, acc, 0, 0, 0);
    }
#pragma unroll
    for (int z = 0; z < 16; ++z)
        pmax[z >> 2] = fmaxf(pmax[z >> 2], acc[z]);
    if ((y & 7) == 7) {
#pragma unroll
        for (int rc = 0; rc < 4; ++rc)
            pmax[rc] = fmaxf(pmax[rc], __shfl_xor(pmax[rc], 32, 64));
        if (half == 0) {
            float bias = cb[m];
            int i = y >> 3;
#pragma unroll
            for (int rc = 0; rc < 4; ++rc) {
                int jc = wv * 4 + rc;
                if (jc < 14)
                    spool[((size_t)vf * 196 + i * 14 + jc) * 32 + m] = pmax[rc] + bias;
            }
        }
    }
    __syncthreads();
    // ---- commit staged rows into circular slots ----
    if (u < 115) {
        int slot = (zz + 16) & 7;
#pragma unroll 1
        for (int p = 0; p < 9; ++p) {
            int c = p / 3, kd = p - c * 3;
            int zf = f + kd - 1;
            bool ok = zok && uok && (0 <= zf) && (zf < 64);
            float vx = ok ? pf[p].x : 0.f, vy = ok ? pf[p].y : 0.f;
            unsigned char* ldp = lds + p * PLANE_PITCH;
            *(u16*)(ldp + u * 16 + slot * 2) = f2bf(vx);
            *(u16*)(ldp + REG_PITCH + u * 16 + slot * 2) = f2bf(vy);
        }
    }
    __syncthreads();
}

__global__ __launch_bounds__(256, 2) void conv_pool_kernel(
    const float* __restrict__ img,   // [256][3][224][224]
    const u16* __restrict__ wprep,   // [64][32][8] bf16 pre-rotated
    const float* __restrict__ cb,
    float* __restrict__ spool)       // [256][196][32]
{
    __shared__ __align__(16) unsigned char lds[CONV_LDS_TOTAL];
    int blk = blockIdx.x;            // 512 = 256 vf * 2 halves
    int hh = blk & 1;
    int vf = blk >> 1;
    int f  = vf & 63;
    int tid  = threadIdx.x;
    int lane = tid & 63;
    int wv   = tid >> 6;
    int m    = lane & 31;
    int half = lane >> 5;
    int x  = wv * 32 + m;
    int xe = x > 111 ? 111 : x;

    // ---- hoist B fragments into registers (once) ----
    short8 Bc[32];
#pragma unroll
    for (int kk = 0; kk < 32; ++kk)
        Bc[kk] = *(const short8*)(wprep + (((size_t)(2 * kk + half) * 32 + m) << 3));

    int u = tid & 127;               // staging column (valid < 115)
    int rowsel = tid >> 7;
    int y0 = 56 * hh;

    // ---- initial prime: rows 2y0-3 .. 2y0+3 real, slot of 2y0+4 zeroed ----
    for (int rnd = 0; rnd < 4; ++rnd) {
        int zz = 2 * y0 - 3 + 2 * rnd + rowsel;
        bool force0 = (2 * rnd + rowsel) == 7;
        int zc = zz < 0 ? 0 : (zz > 223 ? 223 : zz);
        bool zok = ((unsigned)zz < 224u) && !force0;
        int col = 2 * u - 4;
        int colc = col < 0 ? 0 : (col > 222 ? 222 : col);
        bool uok = (u >= 2 && u <= 113);
        if (u < 115) {
            int slot = (zz + 16) & 7;
#pragma unroll 1
            for (int p = 0; p < 9; ++p) {
                int c = p / 3, kd = p - c * 3;
                int zf = f + kd - 1;
                int zp = vf + kd - 1;
                int zpc = zp < 0 ? 0 : (zp > 255 ? 255 : zp);
                bool ok = zok && uok && (0 <= zf) && (zf < 64);
                float2 pv = *(const float2*)(img + ((size_t)zpc * 3 + c) * IMG_PIX
                                             + (size_t)zc * 224 + colc);
                float vx = ok ? pv.x : 0.f, vy = ok ? pv.y : 0.f;
                unsigned char* ldp = lds + p * PLANE_PITCH;
                *(u16*)(ldp + u * 16 + slot * 2) = f2bf(vx);
                *(u16*)(ldp + REG_PITCH + u * 16 + slot * 2) = f2bf(vy);
            }
        }
    }
    __syncthreads();

    float pmax[4];
    // y&3 cycle: 0,1,2,3 -> E = 2,0,6,4 (RL = (3-2y)&7, E = RL-1, all even)
    for (int yq = 0; yq < 14; ++yq) {
        int yb = y0 + yq * 4;
        conv_y_body<2>(yb + 0, lds, img, Bc, cb, spool, pmax, vf, f, u, rowsel, xe, half, m, wv);
        conv_y_body<0>(yb + 1, lds, img, Bc, cb, spool, pmax, vf, f, u, rowsel, xe, half, m, wv);
        conv_y_body<6>(yb + 2, lds, img, Bc, cb, spool, pmax, vf, f, u, rowsel, xe, half, m, wv);
        conv_y_body<4>(yb + 3, lds, img, Bc, cb, spool, pmax, vf, f, u, rowsel, xe, half, m, wv);
    }
}

// ---------------- depth maxpool + adjacent-frame avg -> feat image cols ----------------
__global__ void depth_adj_kernel(const float* __restrict__ spool, float* __restrict__ feat) {
    int idx = blockIdx.x * 256 + threadIdx.x;
    if (idx >= NREC * IMGF) return;
    int col = idx % IMGF;
    int r   = idx / IMGF;
    int o  = col / 196, ij = col % 196;
    int g  = r / 15, jj = r % 15;
    int tt = 16 * g + jj;
    int v  = tt >> 6, f = tt & 63;
    const int FS = 196 * 32;
    const float* S = spool + ((size_t)(v * 64) * 196 + ij) * 32 + o;
    float a = S[(size_t)f * FS];
    if (f > 0) a = fmaxf(a, S[(size_t)(f - 1) * FS]);
    a = fmaxf(a, S[(size_t)(f + 1) * FS]);
    int f2 = f + 1;
    float b = fmaxf(S[(size_t)f2 * FS], S[(size_t)(f2 - 1) * FS]);
    if (f2 + 1 < 64) b = fmaxf(b, S[(size_t)(f2 + 1) * FS]);
    feat[(size_t)r * FEATD + col] = 0.5f * (a + b);
}

// ---------------- embedding gather -> bf16 [7680][320] (zero-padded) ----------------
__global__ void embed_bf_kernel(const int* __restrict__ txt, const float* __restrict__ emb,
                                u16* __restrict__ x0b) {
    int idx = blockIdx.x * 256 + threadIdx.x;
    if (idx >= NROW * 320) return;
    int e = idx % 320, nt = idx / 320;
    x0b[idx] = (e < EDIM) ? f2bf(emb[(size_t)txt[nt] * EDIM + e]) : (u16)0;
}

// ---------------- pre-gate GEMM via MFMA: out[d][m][j] = A[m,:].W[d][j,:] + b1+b2
#define PGP 40   // LDS row pitch in shorts (80 B)
__global__ __launch_bounds__(256) void pregate_mfma(
    const u16* __restrict__ A,    // [7680][Kp] bf16
    const u16* __restrict__ W,    // [2][1024][Kp] bf16
    const float* __restrict__ b1, const float* __restrict__ b2,
    float* __restrict__ out, int Kp)
{
    __shared__ __align__(16) u16 a_s[128 * PGP];
    __shared__ __align__(16) u16 b_s[128 * PGP];
    int d  = blockIdx.z;
    int m0 = blockIdx.x * 128;
    int j0 = blockIdx.y * 128;
    const u16* Wd = W + (size_t)d * G4 * Kp;
    float* outd = out + (size_t)d * NROW * G4;
    int tid = threadIdx.x;
    int lane = tid & 63;
    int wv = tid >> 6;
    int wm = wv & 1, wn = wv >> 1;
    int ln31 = lane & 31, lh = lane >> 5;
    floatx16 acc[2][2];
#pragma unroll
    for (int a = 0; a < 2; a++)
#pragma unroll
        for (int b = 0; b < 2; b++) {
            floatx16 z = {0,0,0,0,0,0,0,0,0,0,0,0,0,0,0,0};
            acc[a][b] = z;
        }
    for (int k0 = 0; k0 < Kp; k0 += 32) {
#pragma unroll
        for (int li = 0; li < 2; li++) {
            int e = tid + li * 256;
            int row = e >> 2, part = e & 3;
            uint4 va = *(const uint4*)(A + (size_t)(m0 + row) * Kp + k0 + part * 8);
            *(uint4*)&a_s[row * PGP + part * 8] = va;
            uint4 vb = *(const uint4*)(Wd + (size_t)(j0 + row) * Kp + k0 + part * 8);
            *(uint4*)&b_s[row * PGP + part * 8] = vb;
        }
        __syncthreads();
#pragma unroll
        for (int kk = 0; kk < 2; kk++) {
            int ko = kk * 16 + lh * 8;
            short8 a0 = *(const short8*)&a_s[(wm * 64 + ln31) * PGP + ko];
            short8 a1 = *(const short8*)&a_s[(wm * 64 + 32 + ln31) * PGP + ko];
            short8 b0 = *(const short8*)&b_s[(wn * 64 + ln31) * PGP + ko];
            short8 b1v = *(const short8*)&b_s[(wn * 64 + 32 + ln31) * PGP + ko];
            acc[0][0] = __builtin_amdgcn_mfma_f32_32x32x16_bf16(a0, b0, acc[0][0], 0, 0, 0);
            acc[0][1] = __builtin_amdgcn_mfma_f32_32x32x16_bf16(a0, b1v, acc[0][1], 0, 0, 0);
            acc[1][0] = __builtin_amdgcn_mfma_f32_32x32x16_bf16(a1, b0, acc[1][0], 0, 0, 0);
            acc[1][1] = __builtin_amdgcn_mfma_f32_32x32x16_bf16(a1, b1v, acc[1][1], 0, 0, 0);
        }
        __syncthreads();
    }
#pragma unroll
    for (int mi = 0; mi < 2; mi++)
#pragma unroll
        for (int ni = 0; ni < 2; ni++) {
#pragma unroll
            for (int rg = 0; rg < 16; rg++) {
                int row = m0 + wm * 64 + mi * 32 + (rg & 3) + 8 * (rg >> 2) + 4 * lh;
                int colj = j0 + wn * 64 + ni * 32 + ln31;
                outd[(size_t)row * G4 + colj] =
                    acc[mi][ni][rg] + b1[d * G4 + colj] + b2[d * G4 + colj];
            }
        }
}

// ---------------- recurrent LSTM (fp16 weights + dot2), one layer, both dirs ----------
__global__ __launch_bounds__(256) void lstm_kernel(
    const float* __restrict__ pre,     // [2][7680][1024] fp32
    const _Float16* __restrict__ whh,  // [2 d][128 k2][256 hu][4 g][2] fp16
    const int* __restrict__ lens,
    float* __restrict__ houtf,         // [7680][512] fp32 (if !obf)
    u16* __restrict__ houtb,           // [7680][512] bf16 (if obf)
    int obf)
{
    int d  = blockIdx.y;
    int n0 = blockIdx.x * 3;
    int hu = threadIdx.x;
    __shared__ __align__(16) _Float16 hs[2][3][256];
    float h[3] = {0.f, 0.f, 0.f}, c[3] = {0.f, 0.f, 0.f};
    int len[3] = {lens[n0], lens[n0 + 1], lens[n0 + 2]};
    hs[0][0][hu] = (_Float16)0.f; hs[0][1][hu] = (_Float16)0.f; hs[0][2][hu] = (_Float16)0.f;
    __syncthreads();
    int cur = 0;
    const _Float16* wb = whh + (size_t)d * 262144;
    const float* preb = pre + (size_t)d * NROW * G4;
    for (int ss = 0; ss < 32; ss++) {
        int t = d ? (31 - ss) : ss;
        float ai[3], af[3], ag[3], ao[3];
#pragma unroll
        for (int b = 0; b < 3; b++) {
            const float* pp = preb + ((size_t)(n0 + b) * TT + t) * G4 + hu;
            ai[b] = pp[0]; af[b] = pp[256]; ag[b] = pp[512]; ao[b] = pp[768];
        }
#pragma unroll 4
        for (int k2 = 0; k2 < 128; k2++) {
            uint4 wr = *(const uint4*)(wb + ((size_t)k2 * 256 + hu) * 8);
            h2 wi = __builtin_bit_cast(h2, wr.x);
            h2 wf = __builtin_bit_cast(h2, wr.y);
            h2 wg = __builtin_bit_cast(h2, wr.z);
            h2 wo = __builtin_bit_cast(h2, wr.w);
#pragma unroll
            for (int b = 0; b < 3; b++) {
                h2 hv = *(const h2*)&hs[cur][b][2 * k2];
#if __has_builtin(__builtin_amdgcn_fdot2)
                ai[b] = __builtin_amdgcn_fdot2(wi, hv, ai[b], false);
                af[b] = __builtin_amdgcn_fdot2(wf, hv, af[b], false);
                ag[b] = __builtin_amdgcn_fdot2(wg, hv, ag[b], false);
                ao[b] = __builtin_amdgcn_fdot2(wo, hv, ao[b], false);
#else
                ai[b] += (float)wi.x * (float)hv.x + (float)wi.y * (float)hv.y;
                af[b] += (float)wf.x * (float)hv.x + (float)wf.y * (float)hv.y;
                ag[b] += (float)wg.x * (float)hv.x + (float)wg.y * (float)hv.y;
                ao[b] += (float)wo.x * (float)hv.x + (float)wo.y * (float)hv.y;
#endif
            }
        }
        int nxt = cur ^ 1;
#pragma unroll
        for (int b = 0; b < 3; b++) {
            float iv = 1.f / (1.f + expf(-ai[b]));
            float fv = 1.f / (1.f + expf(-af[b]));
            float gv = tanhf(ag[b]);
            float ov = 1.f / (1.f + expf(-ao[b]));
            float cn = fmaf(fv, c[b], iv * gv);
            float hn = ov * tanhf(cn);
            bool mk = t < len[b];
            float outv = mk ? hn : 0.f;
            if (mk) { c[b] = cn; h[b] = hn; }
            size_t oidx = ((size_t)(n0 + b) * TT + t) * 512 + d * 256 + hu;
            if (obf) houtb[oidx] = f2bf(outv);
            else     houtf[oidx] = outv;
            hs[nxt][b][hu] = (_Float16)h[b];
        }
        __syncthreads();
        cur = nxt;
    }
}

// ---------------- masked mean over time -> feat rnn cols ----------------
__global__ void rnn_avg_kernel(const float* __restrict__ h1, const int* __restrict__ lens,
                               float* __restrict__ feat) {
    int idx = blockIdx.x * 256 + threadIdx.x;
    if (idx >= NREC * 512) return;
    int n = idx >> 9, cd = idx & 511;
    float s = 0.f;
    for (int t = 0; t < TT; t++) s += h1[((size_t)n * TT + t) * 512 + cd];
    feat[(size_t)n * FEATD + IMGF + cd] = s / (float)lens[n];
}

// ---------------- final linear + sigmoid ----------------
__global__ __launch_bounds__(256) void final_kernel(const float* __restrict__ feat,
                                                    const float* __restrict__ lw,
                                                    const float* __restrict__ lb,
                                                    float* __restrict__ scores) {
    int n = blockIdx.x;
    float acc[NCLS];
#pragma unroll
    for (int cc = 0; cc < NCLS; cc++) acc[cc] = 0.f;
    for (int k = threadIdx.x; k < FEATD; k += 256) {
        float fv = feat[(size_t)n * FEATD + k];
#pragma unroll
        for (int cc = 0; cc < NCLS; cc++)
            acc[cc] = fmaf(fv, lw[cc * FEATD + k], acc[cc]);
    }
#pragma unroll
    for (int cc = 0; cc < NCLS; cc++) {
#pragma unroll
        for (int off = 32; off >= 1; off >>= 1)
            acc[cc] += __shfl_xor(acc[cc], off, 64);
    }
    __shared__ float red[NCLS][4];
    int lane = threadIdx.x & 63, wid = threadIdx.x >> 6;
    if (lane == 0)
        for (int cc = 0; cc < NCLS; cc++) red[cc][wid] = acc[cc];
    __syncthreads();
    if (threadIdx.x < NCLS) {
        float s = red[threadIdx.x][0] + red[threadIdx.x][1] + red[threadIdx.x][2] +
                  red[threadIdx.x][3] + lb[threadIdx.x];
        scores[n * NCLS + threadIdx.x] = 1.f / (1.f + expf(-s));
    }
}

// ---------------- per-video max over 60 records ----------------
__global__ void vidmax_kernel(const float* __restrict__ scores, float* __restrict__ out) {
    int idx = threadIdx.x;
    if (idx < NV * NCLS) {
        int v = idx / NCLS, cc = idx % NCLS;
        float m = -3.0e38f;
        for (int r = 0; r < 60; r++)
            m = fmaxf(m, scores[(v * 60 + r) * NCLS + cc]);
        out[idx] = m;
    }
}

extern "C" void kernel_launch(void* const* d_in, const int* in_sizes, int n_in,
                              void* d_out, int out_size, void* d_ws, size_t ws_size,
                              hipStream_t stream) {
    (void)in_sizes; (void)n_in; (void)out_size; (void)ws_size;
    const float* img  = (const float*)d_in[0];
    const int*   txt  = (const int*)d_in[1];
    const int*   lens = (const int*)d_in[2];
    const float* emb  = (const float*)d_in[7];
    const float* Wih0 = (const float*)d_in[8];
    const float* Whh0 = (const float*)d_in[9];
    const float* bih0 = (const float*)d_in[10];
    const float* bhh0 = (const float*)d_in[11];
    const float* Wih1 = (const float*)d_in[12];
    const float* Whh1 = (const float*)d_in[13];
    const float* bih1 = (const float*)d_in[14];
    const float* bhh1 = (const float*)d_in[15];
    const float* cw   = (const float*)d_in[16];
    const float* cb   = (const float*)d_in[17];
    const float* lw   = (const float*)d_in[18];
    const float* lb   = (const float*)d_in[19];

    char* wsb = (char*)d_ws;
    u16*      wprep = (u16*)wsb;                        // 32768 B
    _Float16* whhH  = (_Float16*)(wsb + 32768);         // 2,097,152 B
    u16*      wihb0 = (u16*)(wsb + 2129920);            // 1,310,720 B  [2][1024][320]
    u16*      wihb1 = (u16*)(wsb + 3440640);            // 2,097,152 B  [2][1024][512]
    u16*      x0b   = (u16*)(wsb + 5537792);            // 4,915,200 B  [7680][320]
    float*    pre   = (float*)(wsb + 10452992);         // 62,914,560 B [2][7680][1024]
    u16*      h0b   = (u16*)(wsb + 73367552);           // 7,864,320 B  [7680][512]
    float*    h1o   = (float*)(wsb + 81231872);         // 15,728,640 B
    float*    spool = (float*)(wsb + 96960512);         // 6,422,528 B  [256][196][32]
    float*    feat  = (float*)(wsb + 103383040);        // 6,512,640 B
    float*    scor  = (float*)(wsb + 109895680);        // 19,200 B

    prep_all_kernel<<<4096, 256, 0, stream>>>(cw, Whh0, Whh1, Wih0, Wih1,
                                              wprep, whhH, wihb0, wihb1);
    conv_pool_kernel<<<512, 256, 0, stream>>>(img, wprep, cb, spool);
    depth_adj_kernel<<<5880, 256, 0, stream>>>(spool, feat);
    embed_bf_kernel<<<9600, 256, 0, stream>>>(txt, emb, x0b);
    pregate_mfma<<<dim3(60, 8, 2), 256, 0, stream>>>(x0b, wihb0, bih0, bhh0, pre, 320);
    lstm_kernel<<<dim3(80, 2), 256, 0, stream>>>(pre, whhH, lens, h1o, h0b, 1);
    pregate_mfma<<<dim3(60, 8, 2), 256, 0, stream>>>(h0b, wihb1, bih1, bhh1, pre, 512);
    lstm_kernel<<<dim3(80, 2), 256, 0, stream>>>(pre, whhH + 524288, lens, h1o, h0b, 0);
    rnn_avg_kernel<<<480, 256, 0, stream>>>(h1o, lens, feat);
    final_kernel<<<240, 256, 0, stream>>>(feat, lw, lb, scor);
    vidmax_kernel<<<1, 128, 0, stream>>>(scor, (float*)d_out);
}